// Round 12
// baseline (271.580 us; speedup 1.0000x reference)
//
#include <hip/hip_runtime.h>
#include <stdint.h>

#define BB 8
#define NPT 8192
#define SPT 2048
#define C1D 128
#define C2D 256
#define CIN 384
#define HD 256
#define SPLIT 8
#define SC (SPT/SPLIT)   // 256 source points per chunk

typedef __attribute__((ext_vector_type(8))) short bf16x8;
typedef __attribute__((ext_vector_type(4))) float f32x4;

__device__ __forceinline__ unsigned short f2b(float f){
  unsigned int u = __float_as_uint(f);
  u += 0x7fffu + ((u >> 16) & 1u);   // RNE; inputs finite
  return (unsigned short)(u >> 16);
}

// Workgroup barrier that does NOT drain vmcnt (prefetched global loads stay in
// flight) but IS safe against the rule-18 compiler trap: register-only MFMA is
// not ordered by an asm "memory" clobber, so without sched_barrier(0) the
// scheduler can sink MFMAs (and their covering lgkmcnt waits) past s_barrier.
// sched_barrier(0) pins ALL instructions; lgkmcnt(0) covers LDS ops. vmcnt
// untouched — the whole point vs __syncthreads (R7: 66->83us regression).
__device__ __forceinline__ void bar_sync(){
  __builtin_amdgcn_sched_barrier(0);
  asm volatile("s_waitcnt lgkmcnt(0)" ::: "memory");
  __builtin_amdgcn_s_barrier();
  __builtin_amdgcn_sched_barrier(0);
}

// ---------------- FUSED PREP: cvt(W1,W2) | gsrc | transpose(fea2) | transpose(fea1) --------------
// Four independent prep jobs in ONE dispatch (block-range dispatch, block-uniform branches).
// Bodies are byte-identical to the previously proven separate kernels. Cuts 3 kernel
// boundaries (each = dispatch teardown + cross-XCD L2 release on MI355X).
#define NB_CVT 640                     // (HD*CIN + HD*HD)/256
#define NB_GSRC 64                     // BB*SPT/256
#define NB_T2 4096                     // (SPT/32)*(C2D/32)*BB
#define NB_T1 8192                     // (NPT/32)*(C1D/32)*BB
__global__ __launch_bounds__(256) void prep_kernel(
    const float* __restrict__ W1, const float* __restrict__ W2, unsigned short* __restrict__ Wb,
    const float* __restrict__ coor2, const unsigned char* __restrict__ pad, float4* __restrict__ gs,
    const float* __restrict__ fea2, unsigned short* __restrict__ f2t,
    const float* __restrict__ fea1, unsigned short* __restrict__ xpm){
  __shared__ unsigned short t[32][33];
  int bid = blockIdx.x, tid = threadIdx.x;
  if (bid < NB_CVT){
    int i = bid * 256 + tid;
    const int n1 = HD * CIN;
    if (i < n1) Wb[i] = f2b(W1[i]);
    else { int k = i - n1; if (k < HD * HD) Wb[n1 + k] = f2b(W2[k]); }
    return;
  }
  bid -= NB_CVT;
  if (bid < NB_GSRC){
    int i = bid * 256 + tid;                 // i in [0, BB*SPT)
    int b = i >> 11, s = i & (SPT - 1);
    const float* cb = coor2 + b * 3 * SPT;
    float x = cb[s], y = cb[SPT + s], z = cb[2*SPT + s];
    if (pad[i]) { x = 1e19f; y = 1e19f; z = 1e19f; }
    float n2 = __fadd_rn(__fadd_rn(__fmul_rn(x,x), __fmul_rn(y,y)), __fmul_rn(z,z));
    gs[i] = make_float4(x, y, z, n2);
    return;
  }
  bid -= NB_GSRC;
  // transpose job: [B,C,N] f32 -> [B,N,C(dstStride)] bf16
  const float* src; unsigned short* dst; int Cdim, Ndim, dstStride, n0, c0, b;
  if (bid < NB_T2){
    src = fea2; dst = f2t; Cdim = C2D; Ndim = SPT; dstStride = C2D;
    n0 = (bid & 63) * 32; c0 = ((bid >> 6) & 7) * 32; b = bid >> 9;
  } else {
    bid -= NB_T2;
    src = fea1; dst = xpm; Cdim = C1D; Ndim = NPT; dstStride = CIN;
    n0 = (bid & 255) * 32; c0 = ((bid >> 8) & 3) * 32; b = bid >> 10;
  }
  int tx = tid & 31, ty = tid >> 5;
  const float* s = src + (size_t)b * Cdim * Ndim;
  unsigned short* d = dst + (size_t)b * Ndim * dstStride;
  #pragma unroll
  for (int i = 0; i < 4; i++)
    t[ty + i*8][tx] = f2b(s[(size_t)(c0 + ty + i*8) * Ndim + n0 + tx]);
  __syncthreads();
  #pragma unroll
  for (int i = 0; i < 4; i++)
    d[(size_t)(n0 + ty + i*8) * dstStride + c0 + tx] = t[tx][ty + i*8];
}

// ---------------- 3-NN partial scan over one S-chunk (proven scalar version, FROZEN) ----------------
// Source points via LOOP-UNIFORM global reads -> s_load into SGPRs (SMEM pipe, no LDS,
// zero LDS => high occupancy). Straight-line unrolled body keeps the s_load stream
// software-pipelined. Three failed attacks (R1 pair-SoA, R4 wave-any guard, R11 pk-asm)
// each broke the pipeline a different way — 64us @ 88% VALUBusy is this loop's floor.
// Distance math bit-exact vs numpy: dot = fl(fl(xx)+fl(yy))+fl(zz),
// d = fma(-2,dot,fl(n1+n2)).
__global__ __launch_bounds__(256) void knn_part_kernel(const float* __restrict__ coor1,
    const float4* __restrict__ gs, float* __restrict__ cv, int* __restrict__ cj){
  int b = blockIdx.y, c = blockIdx.z;
  int s0c = c * SC;
  const float4* gsb = gs + b * SPT + s0c;
  int n = blockIdx.x * 256 + threadIdx.x;
  const float* ca = coor1 + b * 3 * NPT;
  float x1 = ca[n], y1 = ca[NPT + n], z1 = ca[2*NPT + n];
  float n1 = __fadd_rn(__fadd_rn(__fmul_rn(x1,x1), __fmul_rn(y1,y1)), __fmul_rn(z1,z1));
  float v0 = 3.4e38f, v1 = 3.4e38f, v2 = 3.4e38f;
  int j0 = 0, j1 = 0, j2 = 0;
  #pragma unroll 8
  for (int s = 0; s < SC; s++){
    float4 q = gsb[s];                       // uniform address -> SGPR load
    float dot = __fadd_rn(__fadd_rn(__fmul_rn(x1,q.x), __fmul_rn(y1,q.y)), __fmul_rn(z1,q.z));
    float npn = __fadd_rn(n1, q.w);
    float d = __builtin_fmaf(-2.0f, dot, npn);
    bool l0 = d < v0, l1 = d < v1, l2 = d < v2;  // strict < keeps earliest index on ties
    j2 = l1 ? j1 : (l2 ? s : j2);
    j1 = l0 ? j0 : (l1 ? s : j1);
    j0 = l0 ? s  : j0;
    float nv2 = __builtin_amdgcn_fmed3f(v1, v2, d);
    float nv1 = __builtin_amdgcn_fmed3f(v0, v1, d);
    v0 = fminf(v0, d); v1 = nv1; v2 = nv2;
  }
  size_t m = (size_t)b * NPT + n;
  size_t base = (m * SPLIT + c) * 3;
  cv[base+0] = v0; cv[base+1] = v1; cv[base+2] = v2;
  cj[base+0] = s0c + j0; cj[base+1] = s0c + j1; cj[base+2] = s0c + j2;
}

// ---------------- FUSED merge + gather/interp -> xpm[:,128:384] bf16 ----------------
// Per point: all 64 lanes of its group redundantly merge the SPLIT x top-3 partials
// (same-address scalar loads broadcast to one transaction; 24x11 VALU ops is trivial
// vs gather latency), then the group gathers 3 x 512B f2t rows and blends.
// Kills the knn_merge launch + the w3/i3 round-trip.
__global__ __launch_bounds__(256) void interp_kernel(const float* __restrict__ cv,
    const int* __restrict__ cj, const unsigned short* __restrict__ f2t,
    unsigned short* __restrict__ xpm){
  int m = blockIdx.x * 4 + (threadIdx.x >> 6);
  int lane = threadIdx.x & 63;
  int b = m >> 13;
  float v0 = 3.4e38f, v1 = 3.4e38f, v2 = 3.4e38f;
  int j0 = 0, j1 = 0, j2 = 0;
  // chunk-ascending insert order + strict < == global sequential scan tie-order
  #pragma unroll
  for (int c = 0; c < SPLIT; c++){
    #pragma unroll
    for (int k = 0; k < 3; k++){
      float d = cv[((size_t)m * SPLIT + c) * 3 + k];
      int j   = cj[((size_t)m * SPLIT + c) * 3 + k];
      bool l0 = d < v0, l1 = d < v1, l2 = d < v2;
      j2 = l1 ? j1 : (l2 ? j : j2);
      j1 = l0 ? j0 : (l1 ? j : j1);
      j0 = l0 ? j  : j0;
      float nv2 = __builtin_amdgcn_fmed3f(v1, v2, d);
      float nv1 = __builtin_amdgcn_fmed3f(v0, v1, d);
      v0 = fminf(v0, d); v1 = nv1; v2 = nv2;
    }
  }
  float r0 = 1.0f / fmaxf(v0, 1e-8f);
  float r1 = 1.0f / fmaxf(v1, 1e-8f);
  float r2 = 1.0f / fmaxf(v2, 1e-8f);
  float rs = (r0 + r1) + r2;
  float w0 = r0 / rs, w1 = r1 / rs, w2 = r2 / rs;
  const ushort4 a = *(const ushort4*)(f2t + (size_t)(b*SPT + j0) * C2D + lane*4);
  const ushort4 c = *(const ushort4*)(f2t + (size_t)(b*SPT + j1) * C2D + lane*4);
  const ushort4 e = *(const ushort4*)(f2t + (size_t)(b*SPT + j2) * C2D + lane*4);
  #define B2F(u) __uint_as_float(((unsigned int)(u)) << 16)
  ushort4 o;
  o.x = f2b(w0*B2F(a.x) + w1*B2F(c.x) + w2*B2F(e.x));
  o.y = f2b(w0*B2F(a.y) + w1*B2F(c.y) + w2*B2F(e.y));
  o.z = f2b(w0*B2F(a.z) + w1*B2F(c.z) + w2*B2F(e.z));
  o.w = f2b(w0*B2F(a.w) + w1*B2F(c.w) + w2*B2F(e.w));
  *(ushort4*)(xpm + (size_t)m * CIN + C1D + lane*4) = o;
}

// ---------------- FUSED MLP: GEMM1(K=384)+LN+relu -> H in LDS -> GEMM2(K=256)+LN+relu -> out ----
// R9 proven version (VGPR 120, params in LDS — R10's param-LDS removal blew VGPR to 176
// and regressed; reverted). Single-buffer Ws + register-prefetch (T14) + bar_sync
// barriers (lgkmcnt-only drain; prefetched global loads stay in flight across barriers).
__global__ __launch_bounds__(256) void mlp_fused_kernel(const unsigned short* __restrict__ xpm,
    const unsigned short* __restrict__ W1g, const unsigned short* __restrict__ W2g,
    const float* __restrict__ b1, const float* __restrict__ g1, const float* __restrict__ be1,
    const float* __restrict__ b2, const float* __restrict__ g2, const float* __restrict__ be2,
    float* __restrict__ outg){
  __shared__ __align__(16) unsigned short Ws[256*40];     // W chunk [256 o][32 k] pad->40 (both phases)
  __shared__ __align__(16) unsigned short Hbuf[64*264];   // H [64 m][256 k] pad->264; front aliases Xs
  __shared__ float sB[256], sG[256], sBe[256];
  unsigned short* Xs = Hbuf;                              // phase-1 X staging [64 m][32 k] pad->40
  int tid = threadIdx.x;
  int m0 = blockIdx.x * 64;
  int b = m0 >> 13, n0 = m0 & (NPT - 1);
  sB[tid] = b1[tid]; sG[tid] = g1[tid]; sBe[tid] = be1[tid];
  int w = tid >> 6, lane = tid & 63, col = lane & 15, quad = lane >> 4;
  int ml = w*16 + col;                                    // this lane's point row (0..63)
  int mr = tid >> 2, part = tid & 3;                      // X staging assignment
  const int4* wsrc  = (const int4*)(W1g + (size_t)tid * CIN);        // 4 int4 per 32-k chunk
  const int4* xsrc  = (const int4*)(xpm + (size_t)(m0 + mr) * CIN + part*8); // chunk stride = 4 int4
  f32x4 acc[16];
  #pragma unroll
  for (int i = 0; i < 16; i++) acc[i] = (f32x4)0.0f;

  // ---------------- phase 1: H = relu(LN1(W1 @ x + b1)) ----------------
  // prologue: chunk 0 into registers
  int4 wA0 = wsrc[0], wA1 = wsrc[1], wA2 = wsrc[2], wA3 = wsrc[3];
  int4 xA  = xsrc[0];
  for (int c = 0; c < 12; c++){
    bar_sync();                         // previous chunk's LDS readers drained (vmcnt untouched)
    {
      int4* d4 = (int4*)(Ws + tid * 40);
      d4[0] = wA0; d4[1] = wA1; d4[2] = wA2; d4[3] = wA3;
      *(int4*)(Xs + mr*40 + part*8) = xA;
    }
    if (c + 1 < 12){                    // issue next chunk's loads NOW; they stay in flight
      wA0 = wsrc[(c+1)*4 + 0]; wA1 = wsrc[(c+1)*4 + 1];
      wA2 = wsrc[(c+1)*4 + 2]; wA3 = wsrc[(c+1)*4 + 3];
      xA  = xsrc[(c+1)*4];              // +32 shorts = +4 int4
    }
    bar_sync();                         // staged writes visible; prefetch still in flight
    bf16x8 bfrag = *(const bf16x8*)(Xs + ml*40 + quad*8);
    #pragma unroll
    for (int ot = 0; ot < 16; ot++){
      bf16x8 afrag = *(const bf16x8*)(Ws + (ot*16 + col)*40 + quad*8);
      acc[ot] = __builtin_amdgcn_mfma_f32_16x16x32_bf16(afrag, bfrag, acc[ot], 0, 0, 0);
    }
  }
  // issue phase-2 prologue loads early: W2 chunk 0 + layer-2 params
  const int4* w2src = (const int4*)(W2g + (size_t)tid * HD);
  int4 v0r = w2src[0], v1r = w2src[1], v2r = w2src[2], v3r = w2src[3];
  float rb2 = b2[tid], rg2 = g2[tid], rbe2 = be2[tid];
  {
    float s1 = 0.f, s2 = 0.f;
    #pragma unroll
    for (int ot = 0; ot < 16; ot++)
      #pragma unroll
      for (int r = 0; r < 4; r++){
        int o = ot*16 + quad*4 + r;
        float v = acc[ot][r] + sB[o];
        acc[ot][r] = v;
        s1 += v; s2 += v*v;
      }
    s1 += __shfl_xor(s1, 16); s1 += __shfl_xor(s1, 32);
    s2 += __shfl_xor(s2, 16); s2 += __shfl_xor(s2, 32);
    float mu = s1 * (1.f/256.f);
    float rinv = rsqrtf(s2 * (1.f/256.f) - mu*mu + 1e-5f);
    bar_sync();        // last Xs reads drained in all waves before Hbuf overwrites it
    #pragma unroll
    for (int ot = 0; ot < 16; ot++){
      int ob = ot*16 + quad*4;
      ushort4 hv;
      hv.x = f2b(fmaxf((acc[ot][0] - mu) * rinv * sG[ob+0] + sBe[ob+0], 0.f));
      hv.y = f2b(fmaxf((acc[ot][1] - mu) * rinv * sG[ob+1] + sBe[ob+1], 0.f));
      hv.z = f2b(fmaxf((acc[ot][2] - mu) * rinv * sG[ob+2] + sBe[ob+2], 0.f));
      hv.w = f2b(fmaxf((acc[ot][3] - mu) * rinv * sG[ob+3] + sBe[ob+3], 0.f));
      *(ushort4*)(Hbuf + ml*264 + ot*16 + quad*4) = hv;
    }
  }
  bar_sync();          // H writes visible to all; layer-1 param reads drained
  sB[tid] = rb2; sG[tid] = rg2; sBe[tid] = rbe2;

  // ---------------- phase 2: out = relu(LN2(W2 @ H + b2)) ----------------
  #pragma unroll
  for (int i = 0; i < 16; i++) acc[i] = (f32x4)0.0f;
  for (int c = 0; c < 8; c++){
    bar_sync();        // previous chunk's Ws readers drained (iter 0: param writes too)
    {
      int4* d4 = (int4*)(Ws + tid * 40);
      d4[0] = v0r; d4[1] = v1r; d4[2] = v2r; d4[3] = v3r;
    }
    if (c + 1 < 8){
      v0r = w2src[(c+1)*4 + 0]; v1r = w2src[(c+1)*4 + 1];
      v2r = w2src[(c+1)*4 + 2]; v3r = w2src[(c+1)*4 + 3];
    }
    bar_sync();        // Ws writes visible
    bf16x8 bfrag = *(const bf16x8*)(Hbuf + ml*264 + c*32 + quad*8);
    #pragma unroll
    for (int ot = 0; ot < 16; ot++){
      bf16x8 afrag = *(const bf16x8*)(Ws + (ot*16 + col)*40 + quad*8);
      acc[ot] = __builtin_amdgcn_mfma_f32_16x16x32_bf16(afrag, bfrag, acc[ot], 0, 0, 0);
    }
  }
  float s1 = 0.f, s2 = 0.f;
  #pragma unroll
  for (int ot = 0; ot < 16; ot++)
    #pragma unroll
    for (int r = 0; r < 4; r++){
      int o = ot*16 + quad*4 + r;
      float v = acc[ot][r] + sB[o];
      acc[ot][r] = v;
      s1 += v; s2 += v*v;
    }
  s1 += __shfl_xor(s1, 16); s1 += __shfl_xor(s1, 32);
  s2 += __shfl_xor(s2, 16); s2 += __shfl_xor(s2, 32);
  float mu = s1 * (1.f/256.f);
  float rinv = rsqrtf(s2 * (1.f/256.f) - mu*mu + 1e-5f);
  size_t obase = (size_t)b * HD * NPT + n0 + w*16 + col;
  #pragma unroll
  for (int ot = 0; ot < 16; ot++)
    #pragma unroll
    for (int r = 0; r < 4; r++){
      int o = ot*16 + quad*4 + r;
      float v = (acc[ot][r] - mu) * rinv * sG[o] + sBe[o];
      outg[obase + (size_t)o * NPT] = fmaxf(v, 0.f);
    }
}

extern "C" void kernel_launch(void* const* d_in, const int* in_sizes, int n_in,
                              void* d_out, int out_size, void* d_ws, size_t ws_size,
                              hipStream_t stream){
  const float* coor1 = (const float*)d_in[0];
  const float* coor2 = (const float*)d_in[1];
  const float* fea1  = (const float*)d_in[2];
  const float* fea2  = (const float*)d_in[3];
  const unsigned char* pad = (const unsigned char*)d_in[4];
  const float* W1  = (const float*)d_in[5];
  const float* b1  = (const float*)d_in[6];
  const float* g1  = (const float*)d_in[7];
  const float* be1 = (const float*)d_in[8];
  const float* W2  = (const float*)d_in[9];
  const float* b2  = (const float*)d_in[10];
  const float* g2  = (const float*)d_in[11];
  const float* be2 = (const float*)d_in[12];
  float* out = (float*)d_out;

  // ws layout (~94.2 MB, same proven footprint): | (w3/i3 unused) | W1b | W2b | f2t | xpm | scratch
  // cv/cj/gs alias the old Hg region (knn-stage scratch only)
  char* ws = (char*)d_ws;
  unsigned short* W1b  = (unsigned short*)(ws + 1573120);
  unsigned short* f2t  = (unsigned short*)(ws + 1900800);
  unsigned short* xpm  = (unsigned short*)(ws + 10289408);
  float* cv            = (float*)(ws + 60621056);             // knn scratch
  int*   cj            = (int*)  (ws + 60621056 + 6291456);
  float4* gs           = (float4*)(ws + 60621056 + 16777216);

  prep_kernel<<<NB_CVT + NB_GSRC + NB_T2 + NB_T1, 256, 0, stream>>>(
      W1, W2, W1b, coor2, pad, gs, fea2, f2t, fea1, xpm);
  knn_part_kernel<<<dim3(NPT/256, BB, SPLIT), 256, 0, stream>>>(coor1, gs, cv, cj);
  interp_kernel<<<BB*NPT/4, 256, 0, stream>>>(cv, cj, f2t, xpm);
  mlp_fused_kernel<<<BB*NPT/64, 256, 0, stream>>>(xpm, W1b, W1b + HD*CIN, b1, g1, be1, b2, g2, be2, out);
}

// Round 13
// 242.480 us; speedup vs baseline: 1.1200x; 1.1200x over previous
//
#include <hip/hip_runtime.h>
#include <stdint.h>

#define BB 8
#define NPT 8192
#define SPT 2048
#define C1D 128
#define C2D 256
#define CIN 384
#define HD 256
#define SPLIT 8
#define SC (SPT/SPLIT)   // 256 source points per chunk

typedef __attribute__((ext_vector_type(8))) short bf16x8;
typedef __attribute__((ext_vector_type(4))) float f32x4;

__device__ __forceinline__ unsigned short f2b(float f){
  unsigned int u = __float_as_uint(f);
  u += 0x7fffu + ((u >> 16) & 1u);   // RNE; inputs finite
  return (unsigned short)(u >> 16);
}

// Workgroup barrier that does NOT drain vmcnt (prefetched global loads stay in
// flight) but IS safe against the rule-18 compiler trap: register-only MFMA is
// not ordered by an asm "memory" clobber, so without sched_barrier(0) the
// scheduler can sink MFMAs (and their covering lgkmcnt waits) past s_barrier.
// sched_barrier(0) pins ALL instructions; lgkmcnt(0) covers LDS ops. vmcnt
// untouched — the whole point vs __syncthreads (R7: 66->83us regression).
__device__ __forceinline__ void bar_sync(){
  __builtin_amdgcn_sched_barrier(0);
  asm volatile("s_waitcnt lgkmcnt(0)" ::: "memory");
  __builtin_amdgcn_s_barrier();
  __builtin_amdgcn_sched_barrier(0);
}

// ---------------- pack source points: gs[b*SPT+s] = (x,y,z,|c|^2), padding applied ----------------
// Must PRECEDE the main fused kernel (knn reads gs).
__global__ __launch_bounds__(256) void gsrc_kernel(const float* __restrict__ coor2,
    const unsigned char* __restrict__ pad, float4* __restrict__ gs){
  int i = blockIdx.x * 256 + threadIdx.x;      // i in [0, BB*SPT)
  int b = i >> 11, s = i & (SPT - 1);
  const float* cb = coor2 + b * 3 * SPT;
  float x = cb[s], y = cb[SPT + s], z = cb[2*SPT + s];
  if (pad[i]) { x = 1e19f; y = 1e19f; z = 1e19f; }
  float n2 = __fadd_rn(__fadd_rn(__fmul_rn(x,x), __fmul_rn(y,y)), __fmul_rn(z,z));
  gs[i] = make_float4(x, y, z, n2);
}

// ---------------- MAIN FUSED: knn_part (VALU-bound) || cvt + transposes (memory-bound) ------------
// Heterogeneous-block overlap: knn at 51% occupancy / ~0 HBM leaves memory pipes and wave
// slots idle; the independent prep jobs backfill them in the SAME dispatch. knn blocks
// first (start immediately), prep blocks fill in behind. All branches block-uniform;
// bodies byte-identical to the proven standalone kernels (knn FROZEN after 3 failed
// attacks: R1 pair-SoA, R4 wave-any guard, R11 pk-asm — 64us @88% VALUBusy is its floor).
#define NB_KNN 2048                    // (NPT/256) * BB * SPLIT
#define NB_CVT 640                     // (HD*CIN + HD*HD)/256
#define NB_T2 4096                     // (SPT/32)*(C2D/32)*BB
#define NB_T1 8192                     // (NPT/32)*(C1D/32)*BB
__global__ __launch_bounds__(256) void main_kernel(
    const float* __restrict__ coor1, const float4* __restrict__ gs,
    float* __restrict__ cv, int* __restrict__ cj,
    const float* __restrict__ W1, const float* __restrict__ W2, unsigned short* __restrict__ Wb,
    const float* __restrict__ fea2, unsigned short* __restrict__ f2t,
    const float* __restrict__ fea1, unsigned short* __restrict__ xpm){
  __shared__ unsigned short t[32][33];
  int bid = blockIdx.x, tid = threadIdx.x;
  if (bid < NB_KNN){
    // ---- knn_part: 3-NN partial scan over one S-chunk (proven scalar version) ----
    // LOOP-UNIFORM global reads -> s_load into SGPRs; straight-line unrolled body keeps
    // the s_load stream software-pipelined; NO branches in the loop.
    // Distance math bit-exact vs numpy: dot=fl(fl(xx)+fl(yy))+fl(zz); d=fma(-2,dot,fl(n1+n2)).
    int x = bid & 31, b = (bid >> 5) & 7, c = bid >> 8;
    int s0c = c * SC;
    const float4* gsb = gs + b * SPT + s0c;
    int n = x * 256 + tid;
    const float* ca = coor1 + b * 3 * NPT;
    float x1 = ca[n], y1 = ca[NPT + n], z1 = ca[2*NPT + n];
    float n1 = __fadd_rn(__fadd_rn(__fmul_rn(x1,x1), __fmul_rn(y1,y1)), __fmul_rn(z1,z1));
    float v0 = 3.4e38f, v1 = 3.4e38f, v2 = 3.4e38f;
    int j0 = 0, j1 = 0, j2 = 0;
    #pragma unroll 8
    for (int s = 0; s < SC; s++){
      float4 q = gsb[s];                       // uniform address -> SGPR load
      float dot = __fadd_rn(__fadd_rn(__fmul_rn(x1,q.x), __fmul_rn(y1,q.y)), __fmul_rn(z1,q.z));
      float npn = __fadd_rn(n1, q.w);
      float d = __builtin_fmaf(-2.0f, dot, npn);
      bool l0 = d < v0, l1 = d < v1, l2 = d < v2;  // strict < keeps earliest index on ties
      j2 = l1 ? j1 : (l2 ? s : j2);
      j1 = l0 ? j0 : (l1 ? s : j1);
      j0 = l0 ? s  : j0;
      float nv2 = __builtin_amdgcn_fmed3f(v1, v2, d);
      float nv1 = __builtin_amdgcn_fmed3f(v0, v1, d);
      v0 = fminf(v0, d); v1 = nv1; v2 = nv2;
    }
    size_t m = (size_t)b * NPT + n;
    size_t base = (m * SPLIT + c) * 3;
    cv[base+0] = v0; cv[base+1] = v1; cv[base+2] = v2;
    cj[base+0] = s0c + j0; cj[base+1] = s0c + j1; cj[base+2] = s0c + j2;
    return;
  }
  bid -= NB_KNN;
  if (bid < NB_CVT){
    int i = bid * 256 + tid;
    const int n1 = HD * CIN;
    if (i < n1) Wb[i] = f2b(W1[i]);
    else { int k = i - n1; if (k < HD * HD) Wb[n1 + k] = f2b(W2[k]); }
    return;
  }
  bid -= NB_CVT;
  // transpose job: [B,C,N] f32 -> [B,N,C(dstStride)] bf16
  const float* src; unsigned short* dst; int Cdim, Ndim, dstStride, n0, c0, b;
  if (bid < NB_T2){
    src = fea2; dst = f2t; Cdim = C2D; Ndim = SPT; dstStride = C2D;
    n0 = (bid & 63) * 32; c0 = ((bid >> 6) & 7) * 32; b = bid >> 9;
  } else {
    bid -= NB_T2;
    src = fea1; dst = xpm; Cdim = C1D; Ndim = NPT; dstStride = CIN;
    n0 = (bid & 255) * 32; c0 = ((bid >> 8) & 3) * 32; b = bid >> 10;
  }
  int tx = tid & 31, ty = tid >> 5;
  const float* s = src + (size_t)b * Cdim * Ndim;
  unsigned short* d = dst + (size_t)b * Ndim * dstStride;
  #pragma unroll
  for (int i = 0; i < 4; i++)
    t[ty + i*8][tx] = f2b(s[(size_t)(c0 + ty + i*8) * Ndim + n0 + tx]);
  __syncthreads();
  #pragma unroll
  for (int i = 0; i < 4; i++)
    d[(size_t)(n0 + ty + i*8) * dstStride + c0 + tx] = t[tx][ty + i*8];
}

// ---------------- merge SPLIT x top-3 -> global top-3 + weights (R9 proven; one thread/point —
// R12's 64-lane-redundant fusion into interp cost ~14us of VALU) ----------------
__global__ __launch_bounds__(256) void knn_merge_kernel(const float* __restrict__ cv,
    const int* __restrict__ cj, float* __restrict__ w3, int* __restrict__ i3){
  size_t m = (size_t)blockIdx.x * 256 + threadIdx.x;
  float v0 = 3.4e38f, v1 = 3.4e38f, v2 = 3.4e38f;
  int j0 = 0, j1 = 0, j2 = 0;
  // chunk-ascending insert order + strict < == global sequential scan tie-order
  #pragma unroll
  for (int c = 0; c < SPLIT; c++){
    #pragma unroll
    for (int k = 0; k < 3; k++){
      float d = cv[(m * SPLIT + c) * 3 + k];
      int j   = cj[(m * SPLIT + c) * 3 + k];
      bool l0 = d < v0, l1 = d < v1, l2 = d < v2;
      j2 = l1 ? j1 : (l2 ? j : j2);
      j1 = l0 ? j0 : (l1 ? j : j1);
      j0 = l0 ? j  : j0;
      float nv2 = __builtin_amdgcn_fmed3f(v1, v2, d);
      float nv1 = __builtin_amdgcn_fmed3f(v0, v1, d);
      v0 = fminf(v0, d); v1 = nv1; v2 = nv2;
    }
  }
  float r0 = 1.0f / fmaxf(v0, 1e-8f);
  float r1 = 1.0f / fmaxf(v1, 1e-8f);
  float r2 = 1.0f / fmaxf(v2, 1e-8f);
  float rs = (r0 + r1) + r2;
  w3[m*3+0] = r0 / rs; w3[m*3+1] = r1 / rs; w3[m*3+2] = r2 / rs;
  i3[m*3+0] = j0; i3[m*3+1] = j1; i3[m*3+2] = j2;
}

// ---------------- gather + weighted sum -> xpm[:,128:384] bf16 (wave per point) ----------------
__global__ __launch_bounds__(256) void interp_kernel(const unsigned short* __restrict__ f2t,
    const float* __restrict__ w3, const int* __restrict__ i3, unsigned short* __restrict__ xpm){
  int m = blockIdx.x * 4 + (threadIdx.x >> 6);
  int lane = threadIdx.x & 63;
  int b = m >> 13;
  int s0 = i3[m*3+0], s1 = i3[m*3+1], s2 = i3[m*3+2];
  float w0 = w3[m*3+0], w1 = w3[m*3+1], w2 = w3[m*3+2];
  const ushort4 a = *(const ushort4*)(f2t + (size_t)(b*SPT + s0) * C2D + lane*4);
  const ushort4 c = *(const ushort4*)(f2t + (size_t)(b*SPT + s1) * C2D + lane*4);
  const ushort4 e = *(const ushort4*)(f2t + (size_t)(b*SPT + s2) * C2D + lane*4);
  #define B2F(u) __uint_as_float(((unsigned int)(u)) << 16)
  ushort4 o;
  o.x = f2b(w0*B2F(a.x) + w1*B2F(c.x) + w2*B2F(e.x));
  o.y = f2b(w0*B2F(a.y) + w1*B2F(c.y) + w2*B2F(e.y));
  o.z = f2b(w0*B2F(a.z) + w1*B2F(c.z) + w2*B2F(e.z));
  o.w = f2b(w0*B2F(a.w) + w1*B2F(c.w) + w2*B2F(e.w));
  *(ushort4*)(xpm + (size_t)m * CIN + C1D + lane*4) = o;
}

// ---------------- FUSED MLP: GEMM1(K=384)+LN+relu -> H in LDS -> GEMM2(K=256)+LN+relu -> out ----
// R9 proven version (VGPR 120, params in LDS — R10's param-LDS removal blew VGPR to 176
// and regressed; reverted). Single-buffer Ws + register-prefetch (T14) + bar_sync
// barriers (lgkmcnt-only drain; prefetched global loads stay in flight across barriers).
__global__ __launch_bounds__(256) void mlp_fused_kernel(const unsigned short* __restrict__ xpm,
    const unsigned short* __restrict__ W1g, const unsigned short* __restrict__ W2g,
    const float* __restrict__ b1, const float* __restrict__ g1, const float* __restrict__ be1,
    const float* __restrict__ b2, const float* __restrict__ g2, const float* __restrict__ be2,
    float* __restrict__ outg){
  __shared__ __align__(16) unsigned short Ws[256*40];     // W chunk [256 o][32 k] pad->40 (both phases)
  __shared__ __align__(16) unsigned short Hbuf[64*264];   // H [64 m][256 k] pad->264; front aliases Xs
  __shared__ float sB[256], sG[256], sBe[256];
  unsigned short* Xs = Hbuf;                              // phase-1 X staging [64 m][32 k] pad->40
  int tid = threadIdx.x;
  int m0 = blockIdx.x * 64;
  int b = m0 >> 13, n0 = m0 & (NPT - 1);
  sB[tid] = b1[tid]; sG[tid] = g1[tid]; sBe[tid] = be1[tid];
  int w = tid >> 6, lane = tid & 63, col = lane & 15, quad = lane >> 4;
  int ml = w*16 + col;                                    // this lane's point row (0..63)
  int mr = tid >> 2, part = tid & 3;                      // X staging assignment
  const int4* wsrc  = (const int4*)(W1g + (size_t)tid * CIN);        // 4 int4 per 32-k chunk
  const int4* xsrc  = (const int4*)(xpm + (size_t)(m0 + mr) * CIN + part*8); // chunk stride = 4 int4
  f32x4 acc[16];
  #pragma unroll
  for (int i = 0; i < 16; i++) acc[i] = (f32x4)0.0f;

  // ---------------- phase 1: H = relu(LN1(W1 @ x + b1)) ----------------
  // prologue: chunk 0 into registers
  int4 wA0 = wsrc[0], wA1 = wsrc[1], wA2 = wsrc[2], wA3 = wsrc[3];
  int4 xA  = xsrc[0];
  for (int c = 0; c < 12; c++){
    bar_sync();                         // previous chunk's LDS readers drained (vmcnt untouched)
    {
      int4* d4 = (int4*)(Ws + tid * 40);
      d4[0] = wA0; d4[1] = wA1; d4[2] = wA2; d4[3] = wA3;
      *(int4*)(Xs + mr*40 + part*8) = xA;
    }
    if (c + 1 < 12){                    // issue next chunk's loads NOW; they stay in flight
      wA0 = wsrc[(c+1)*4 + 0]; wA1 = wsrc[(c+1)*4 + 1];
      wA2 = wsrc[(c+1)*4 + 2]; wA3 = wsrc[(c+1)*4 + 3];
      xA  = xsrc[(c+1)*4];              // +32 shorts = +4 int4
    }
    bar_sync();                         // staged writes visible; prefetch still in flight
    bf16x8 bfrag = *(const bf16x8*)(Xs + ml*40 + quad*8);
    #pragma unroll
    for (int ot = 0; ot < 16; ot++){
      bf16x8 afrag = *(const bf16x8*)(Ws + (ot*16 + col)*40 + quad*8);
      acc[ot] = __builtin_amdgcn_mfma_f32_16x16x32_bf16(afrag, bfrag, acc[ot], 0, 0, 0);
    }
  }
  // issue phase-2 prologue loads early: W2 chunk 0 + layer-2 params
  const int4* w2src = (const int4*)(W2g + (size_t)tid * HD);
  int4 v0r = w2src[0], v1r = w2src[1], v2r = w2src[2], v3r = w2src[3];
  float rb2 = b2[tid], rg2 = g2[tid], rbe2 = be2[tid];
  {
    float s1 = 0.f, s2 = 0.f;
    #pragma unroll
    for (int ot = 0; ot < 16; ot++)
      #pragma unroll
      for (int r = 0; r < 4; r++){
        int o = ot*16 + quad*4 + r;
        float v = acc[ot][r] + sB[o];
        acc[ot][r] = v;
        s1 += v; s2 += v*v;
      }
    s1 += __shfl_xor(s1, 16); s1 += __shfl_xor(s1, 32);
    s2 += __shfl_xor(s2, 16); s2 += __shfl_xor(s2, 32);
    float mu = s1 * (1.f/256.f);
    float rinv = rsqrtf(s2 * (1.f/256.f) - mu*mu + 1e-5f);
    bar_sync();        // last Xs reads drained in all waves before Hbuf overwrites it
    #pragma unroll
    for (int ot = 0; ot < 16; ot++){
      int ob = ot*16 + quad*4;
      ushort4 hv;
      hv.x = f2b(fmaxf((acc[ot][0] - mu) * rinv * sG[ob+0] + sBe[ob+0], 0.f));
      hv.y = f2b(fmaxf((acc[ot][1] - mu) * rinv * sG[ob+1] + sBe[ob+1], 0.f));
      hv.z = f2b(fmaxf((acc[ot][2] - mu) * rinv * sG[ob+2] + sBe[ob+2], 0.f));
      hv.w = f2b(fmaxf((acc[ot][3] - mu) * rinv * sG[ob+3] + sBe[ob+3], 0.f));
      *(ushort4*)(Hbuf + ml*264 + ot*16 + quad*4) = hv;
    }
  }
  bar_sync();          // H writes visible to all; layer-1 param reads drained
  sB[tid] = rb2; sG[tid] = rg2; sBe[tid] = rbe2;

  // ---------------- phase 2: out = relu(LN2(W2 @ H + b2)) ----------------
  #pragma unroll
  for (int i = 0; i < 16; i++) acc[i] = (f32x4)0.0f;
  for (int c = 0; c < 8; c++){
    bar_sync();        // previous chunk's Ws readers drained (iter 0: param writes too)
    {
      int4* d4 = (int4*)(Ws + tid * 40);
      d4[0] = v0r; d4[1] = v1r; d4[2] = v2r; d4[3] = v3r;
    }
    if (c + 1 < 8){
      v0r = w2src[(c+1)*4 + 0]; v1r = w2src[(c+1)*4 + 1];
      v2r = w2src[(c+1)*4 + 2]; v3r = w2src[(c+1)*4 + 3];
    }
    bar_sync();        // Ws writes visible
    bf16x8 bfrag = *(const bf16x8*)(Hbuf + ml*264 + c*32 + quad*8);
    #pragma unroll
    for (int ot = 0; ot < 16; ot++){
      bf16x8 afrag = *(const bf16x8*)(Ws + (ot*16 + col)*40 + quad*8);
      acc[ot] = __builtin_amdgcn_mfma_f32_16x16x32_bf16(afrag, bfrag, acc[ot], 0, 0, 0);
    }
  }
  float s1 = 0.f, s2 = 0.f;
  #pragma unroll
  for (int ot = 0; ot < 16; ot++)
    #pragma unroll
    for (int r = 0; r < 4; r++){
      int o = ot*16 + quad*4 + r;
      float v = acc[ot][r] + sB[o];
      acc[ot][r] = v;
      s1 += v; s2 += v*v;
    }
  s1 += __shfl_xor(s1, 16); s1 += __shfl_xor(s1, 32);
  s2 += __shfl_xor(s2, 16); s2 += __shfl_xor(s2, 32);
  float mu = s1 * (1.f/256.f);
  float rinv = rsqrtf(s2 * (1.f/256.f) - mu*mu + 1e-5f);
  size_t obase = (size_t)b * HD * NPT + n0 + w*16 + col;
  #pragma unroll
  for (int ot = 0; ot < 16; ot++)
    #pragma unroll
    for (int r = 0; r < 4; r++){
      int o = ot*16 + quad*4 + r;
      float v = (acc[ot][r] - mu) * rinv * sG[o] + sBe[o];
      outg[obase + (size_t)o * NPT] = fmaxf(v, 0.f);
    }
}

extern "C" void kernel_launch(void* const* d_in, const int* in_sizes, int n_in,
                              void* d_out, int out_size, void* d_ws, size_t ws_size,
                              hipStream_t stream){
  const float* coor1 = (const float*)d_in[0];
  const float* coor2 = (const float*)d_in[1];
  const float* fea1  = (const float*)d_in[2];
  const float* fea2  = (const float*)d_in[3];
  const unsigned char* pad = (const unsigned char*)d_in[4];
  const float* W1  = (const float*)d_in[5];
  const float* b1  = (const float*)d_in[6];
  const float* g1  = (const float*)d_in[7];
  const float* be1 = (const float*)d_in[8];
  const float* W2  = (const float*)d_in[9];
  const float* b2  = (const float*)d_in[10];
  const float* g2  = (const float*)d_in[11];
  const float* be2 = (const float*)d_in[12];
  float* out = (float*)d_out;

  // ws layout (~94.2 MB, R9 proven): | w3 | i3 | W1b | W2b | f2t | xpm | scratch
  // cv/cj/gs alias the old Hg region (knn-stage scratch only)
  char* ws = (char*)d_ws;
  float* w3            = (float*)(ws + 256);
  int*   i3            = (int*)  (ws + 786688);
  unsigned short* W1b  = (unsigned short*)(ws + 1573120);
  unsigned short* W2b  = (unsigned short*)(ws + 1769728);
  unsigned short* f2t  = (unsigned short*)(ws + 1900800);
  unsigned short* xpm  = (unsigned short*)(ws + 10289408);
  float* cv            = (float*)(ws + 60621056);             // knn scratch
  int*   cj            = (int*)  (ws + 60621056 + 6291456);
  float4* gs           = (float4*)(ws + 60621056 + 16777216);

  gsrc_kernel<<<BB*SPT/256, 256, 0, stream>>>(coor2, pad, gs);
  main_kernel<<<NB_KNN + NB_CVT + NB_T2 + NB_T1, 256, 0, stream>>>(
      coor1, gs, cv, cj, W1, W2, W1b, fea2, f2t, fea1, xpm);
  knn_merge_kernel<<<BB*NPT/256, 256, 0, stream>>>(cv, cj, w3, i3);
  interp_kernel<<<BB*NPT/4, 256, 0, stream>>>(f2t, w3, i3, xpm);
  mlp_fused_kernel<<<BB*NPT/64, 256, 0, stream>>>(xpm, W1b, W2b, b1, g1, be1, b2, g2, be2, out);
}

// Round 14
// 233.144 us; speedup vs baseline: 1.1649x; 1.0400x over previous
//
#include <hip/hip_runtime.h>
#include <stdint.h>

#define BB 8
#define NPT 8192
#define SPT 2048
#define C1D 128
#define C2D 256
#define CIN 384
#define HD 256
#define SPLIT 8
#define SC (SPT/SPLIT)   // 256 source points per chunk

typedef __attribute__((ext_vector_type(8))) short bf16x8;
typedef __attribute__((ext_vector_type(4))) float f32x4;

#define B2F(u) __uint_as_float(((unsigned int)(u)) << 16)

__device__ __forceinline__ unsigned short f2b(float f){
  unsigned int u = __float_as_uint(f);
  u += 0x7fffu + ((u >> 16) & 1u);   // RNE; inputs finite
  return (unsigned short)(u >> 16);
}

// Workgroup barrier that does NOT drain vmcnt (prefetched global loads stay in
// flight) but IS safe against the rule-18 compiler trap: register-only MFMA is
// not ordered by an asm "memory" clobber, so without sched_barrier(0) the
// scheduler can sink MFMAs (and their covering lgkmcnt waits) past s_barrier.
// sched_barrier(0) pins ALL instructions; lgkmcnt(0) covers LDS ops. vmcnt
// untouched — the whole point vs __syncthreads (R7: 66->83us regression).
__device__ __forceinline__ void bar_sync(){
  __builtin_amdgcn_sched_barrier(0);
  asm volatile("s_waitcnt lgkmcnt(0)" ::: "memory");
  __builtin_amdgcn_s_barrier();
  __builtin_amdgcn_sched_barrier(0);
}

// ---------------- pack source points: gs[b*SPT+s] = (x,y,z,|c|^2), padding applied ----------------
// Must PRECEDE the main fused kernel (knn reads gs).
__global__ __launch_bounds__(256) void gsrc_kernel(const float* __restrict__ coor2,
    const unsigned char* __restrict__ pad, float4* __restrict__ gs){
  int i = blockIdx.x * 256 + threadIdx.x;      // i in [0, BB*SPT)
  int b = i >> 11, s = i & (SPT - 1);
  const float* cb = coor2 + b * 3 * SPT;
  float x = cb[s], y = cb[SPT + s], z = cb[2*SPT + s];
  if (pad[i]) { x = 1e19f; y = 1e19f; z = 1e19f; }
  float n2 = __fadd_rn(__fadd_rn(__fmul_rn(x,x), __fmul_rn(y,y)), __fmul_rn(z,z));
  gs[i] = make_float4(x, y, z, n2);
}

// ---------------- MAIN FUSED: knn_part (VALU-bound) || cvt + transposes (memory-bound) ------------
// R13 proven WIN (+14us): heterogeneous-block overlap — knn at 51% occupancy / ~0 HBM
// leaves memory pipes idle; the independent prep jobs backfill them in the SAME dispatch.
// knn blocks first. All branches block-uniform; knn FROZEN (R1/R4/R11 attacks all lost).
#define NB_KNN 2048                    // (NPT/256) * BB * SPLIT
#define NB_CVT 640                     // (HD*CIN + HD*HD)/256
#define NB_T2 4096                     // (SPT/32)*(C2D/32)*BB
#define NB_T1 8192                     // (NPT/32)*(C1D/32)*BB
__global__ __launch_bounds__(256) void main_kernel(
    const float* __restrict__ coor1, const float4* __restrict__ gs,
    float* __restrict__ cv, int* __restrict__ cj,
    const float* __restrict__ W1, const float* __restrict__ W2, unsigned short* __restrict__ Wb,
    const float* __restrict__ fea2, unsigned short* __restrict__ f2t,
    const float* __restrict__ fea1, unsigned short* __restrict__ xpm){
  __shared__ unsigned short t[32][33];
  int bid = blockIdx.x, tid = threadIdx.x;
  if (bid < NB_KNN){
    // ---- knn_part: 3-NN partial scan over one S-chunk (proven scalar version) ----
    // Distance math bit-exact vs numpy: dot=fl(fl(xx)+fl(yy))+fl(zz); d=fma(-2,dot,fl(n1+n2)).
    int x = bid & 31, b = (bid >> 5) & 7, c = bid >> 8;
    int s0c = c * SC;
    const float4* gsb = gs + b * SPT + s0c;
    int n = x * 256 + tid;
    const float* ca = coor1 + b * 3 * NPT;
    float x1 = ca[n], y1 = ca[NPT + n], z1 = ca[2*NPT + n];
    float n1 = __fadd_rn(__fadd_rn(__fmul_rn(x1,x1), __fmul_rn(y1,y1)), __fmul_rn(z1,z1));
    float v0 = 3.4e38f, v1 = 3.4e38f, v2 = 3.4e38f;
    int j0 = 0, j1 = 0, j2 = 0;
    #pragma unroll 8
    for (int s = 0; s < SC; s++){
      float4 q = gsb[s];                       // uniform address -> SGPR load
      float dot = __fadd_rn(__fadd_rn(__fmul_rn(x1,q.x), __fmul_rn(y1,q.y)), __fmul_rn(z1,q.z));
      float npn = __fadd_rn(n1, q.w);
      float d = __builtin_fmaf(-2.0f, dot, npn);
      bool l0 = d < v0, l1 = d < v1, l2 = d < v2;  // strict < keeps earliest index on ties
      j2 = l1 ? j1 : (l2 ? s : j2);
      j1 = l0 ? j0 : (l1 ? s : j1);
      j0 = l0 ? s  : j0;
      float nv2 = __builtin_amdgcn_fmed3f(v1, v2, d);
      float nv1 = __builtin_amdgcn_fmed3f(v0, v1, d);
      v0 = fminf(v0, d); v1 = nv1; v2 = nv2;
    }
    size_t m = (size_t)b * NPT + n;
    size_t base = (m * SPLIT + c) * 3;
    cv[base+0] = v0; cv[base+1] = v1; cv[base+2] = v2;
    cj[base+0] = s0c + j0; cj[base+1] = s0c + j1; cj[base+2] = s0c + j2;
    return;
  }
  bid -= NB_KNN;
  if (bid < NB_CVT){
    int i = bid * 256 + tid;
    const int n1 = HD * CIN;
    if (i < n1) Wb[i] = f2b(W1[i]);
    else { int k = i - n1; if (k < HD * HD) Wb[n1 + k] = f2b(W2[k]); }
    return;
  }
  bid -= NB_CVT;
  // transpose job: [B,C,N] f32 -> [B,N,C(dstStride)] bf16
  const float* src; unsigned short* dst; int Cdim, Ndim, dstStride, n0, c0, b;
  if (bid < NB_T2){
    src = fea2; dst = f2t; Cdim = C2D; Ndim = SPT; dstStride = C2D;
    n0 = (bid & 63) * 32; c0 = ((bid >> 6) & 7) * 32; b = bid >> 9;
  } else {
    bid -= NB_T2;
    src = fea1; dst = xpm; Cdim = C1D; Ndim = NPT; dstStride = CIN;
    n0 = (bid & 255) * 32; c0 = ((bid >> 8) & 3) * 32; b = bid >> 10;
  }
  int tx = tid & 31, ty = tid >> 5;
  const float* s = src + (size_t)b * Cdim * Ndim;
  unsigned short* d = dst + (size_t)b * Ndim * dstStride;
  #pragma unroll
  for (int i = 0; i < 4; i++)
    t[ty + i*8][tx] = f2b(s[(size_t)(c0 + ty + i*8) * Ndim + n0 + tx]);
  __syncthreads();
  #pragma unroll
  for (int i = 0; i < 4; i++)
    d[(size_t)(n0 + ty + i*8) * dstStride + c0 + tx] = t[tx][ty + i*8];
}

// ---------------- FUSED MLP: merge + interp (block prologue) + GEMM1+LN+relu -> GEMM2+LN+relu ----
// block: 256 thr = 4 waves, 64 points.
// Stage A: 64 threads merge SPLIT x top-3 (contiguous 96B/point reads — once per point,
//          NOT per lane; R12's 64-lane-redundant merge cost ~14us).
// Stage B: wave-per-point x16: gather 3 x 512B f2t rows (L2-resident), blend, write
//          channels 128..383 DIRECTLY into LDS X' (= Hbuf[p][0..255]; H overwrites it
//          after the phase-1 barrier, exactly like Xs did before).
// Phase 1: chunks 0..3 (fea1 ch 0..127) stage via separate small Xs from global xpm;
//          chunks 4..11 read bfrags straight from X' — no staging.
// Kills merge+interp launches AND the 67MB xpm[:,128:384] HBM round-trip.
// LDS: Ws 20480 + Hbuf 33792 + Xs 5120 + params 3072 + sW3/sI3 1536 = 64000 -> 2 blocks/CU.
__global__ __launch_bounds__(256) void mlp_fused_kernel(
    const float* __restrict__ cv, const int* __restrict__ cj,
    const unsigned short* __restrict__ f2t, const unsigned short* __restrict__ xpm,
    const unsigned short* __restrict__ W1g, const unsigned short* __restrict__ W2g,
    const float* __restrict__ b1, const float* __restrict__ g1, const float* __restrict__ be1,
    const float* __restrict__ b2, const float* __restrict__ g2, const float* __restrict__ be2,
    float* __restrict__ outg){
  __shared__ __align__(16) unsigned short Ws[256*40];     // W chunk [256 o][32 k] pad->40 (both phases)
  __shared__ __align__(16) unsigned short Hbuf[64*264];   // phase1: X' ch128..383; then H [64][256]
  __shared__ __align__(16) unsigned short Xs[64*40];      // phase-1 ch0..127 staging [64 m][32 k]
  __shared__ float sB[256], sG[256], sBe[256];
  __shared__ float sW3[64*3];
  __shared__ int   sI3[64*3];
  int tid = threadIdx.x;
  int m0 = blockIdx.x * 64;
  int b = m0 >> 13, n0 = m0 & (NPT - 1);
  int w = tid >> 6, lane = tid & 63, col = lane & 15, quad = lane >> 4;
  int ml = w*16 + col;                                    // this lane's point row (0..63)
  int mr = tid >> 2, part = tid & 3;                      // X staging assignment
  const int4* wsrc  = (const int4*)(W1g + (size_t)tid * CIN);        // 4 int4 per 32-k chunk
  const int4* xsrc  = (const int4*)(xpm + (size_t)(m0 + mr) * CIN + part*8); // chunk stride = 4 int4
  // prologue prefetch issued FIRST: in flight under stages A/B
  int4 wA0 = wsrc[0], wA1 = wsrc[1], wA2 = wsrc[2], wA3 = wsrc[3];
  int4 xA  = xsrc[0];
  sB[tid] = b1[tid]; sG[tid] = g1[tid]; sBe[tid] = be1[tid];

  // ---- stage A: merge (one thread per point; chunk-ascending + strict < == scan tie-order) ----
  if (tid < 64){
    size_t m = (size_t)m0 + tid;
    float v0 = 3.4e38f, v1 = 3.4e38f, v2 = 3.4e38f;
    int j0 = 0, j1 = 0, j2 = 0;
    #pragma unroll
    for (int c = 0; c < SPLIT; c++){
      #pragma unroll
      for (int k = 0; k < 3; k++){
        float d = cv[(m * SPLIT + c) * 3 + k];
        int j   = cj[(m * SPLIT + c) * 3 + k];
        bool l0 = d < v0, l1 = d < v1, l2 = d < v2;
        j2 = l1 ? j1 : (l2 ? j : j2);
        j1 = l0 ? j0 : (l1 ? j : j1);
        j0 = l0 ? j  : j0;
        float nv2 = __builtin_amdgcn_fmed3f(v1, v2, d);
        float nv1 = __builtin_amdgcn_fmed3f(v0, v1, d);
        v0 = fminf(v0, d); v1 = nv1; v2 = nv2;
      }
    }
    float r0 = 1.0f / fmaxf(v0, 1e-8f);
    float r1 = 1.0f / fmaxf(v1, 1e-8f);
    float r2 = 1.0f / fmaxf(v2, 1e-8f);
    float rs = (r0 + r1) + r2;
    sW3[tid*3+0] = r0 / rs; sW3[tid*3+1] = r1 / rs; sW3[tid*3+2] = r2 / rs;
    sI3[tid*3+0] = j0; sI3[tid*3+1] = j1; sI3[tid*3+2] = j2;
  }
  bar_sync();          // sW3/sI3 (and params) visible

  // ---- stage B: interp -> X' in LDS (wave per point, 16 points per wave) ----
  {
    int pbase = w*16;
    #pragma unroll 4
    for (int i = 0; i < 16; i++){
      int p = pbase + i;
      float w0 = sW3[p*3+0], w1 = sW3[p*3+1], w2 = sW3[p*3+2];
      int j0 = sI3[p*3+0], j1 = sI3[p*3+1], j2 = sI3[p*3+2];
      const ushort4 a  = *(const ushort4*)(f2t + (size_t)(b*SPT + j0) * C2D + lane*4);
      const ushort4 c4 = *(const ushort4*)(f2t + (size_t)(b*SPT + j1) * C2D + lane*4);
      const ushort4 e  = *(const ushort4*)(f2t + (size_t)(b*SPT + j2) * C2D + lane*4);
      ushort4 o;
      o.x = f2b(w0*B2F(a.x) + w1*B2F(c4.x) + w2*B2F(e.x));
      o.y = f2b(w0*B2F(a.y) + w1*B2F(c4.y) + w2*B2F(e.y));
      o.z = f2b(w0*B2F(a.z) + w1*B2F(c4.z) + w2*B2F(e.z));
      o.w = f2b(w0*B2F(a.w) + w1*B2F(c4.w) + w2*B2F(e.w));
      *(ushort4*)(Hbuf + p*264 + lane*4) = o;   // X'[p][ch-128]
    }
  }
  f32x4 acc[16];
  #pragma unroll
  for (int i = 0; i < 16; i++) acc[i] = (f32x4)0.0f;

  // ---------------- phase 1: H = relu(LN1(W1 @ x + b1)) ----------------
  for (int c = 0; c < 12; c++){
    bar_sync();                         // readers drained; (c=0: X' writes visible too)
    {
      int4* d4 = (int4*)(Ws + tid * 40);
      d4[0] = wA0; d4[1] = wA1; d4[2] = wA2; d4[3] = wA3;
      if (c < 4) *(int4*)(Xs + mr*40 + part*8) = xA;
    }
    if (c + 1 < 12){                    // issue next chunk's loads NOW; they stay in flight
      wA0 = wsrc[(c+1)*4 + 0]; wA1 = wsrc[(c+1)*4 + 1];
      wA2 = wsrc[(c+1)*4 + 2]; wA3 = wsrc[(c+1)*4 + 3];
      if (c + 1 < 4) xA = xsrc[(c+1)*4];   // +32 shorts = +4 int4
    }
    bar_sync();                         // staged writes visible; prefetch still in flight
    bf16x8 bfrag = (c < 4)
      ? *(const bf16x8*)(Xs + ml*40 + quad*8)
      : *(const bf16x8*)(Hbuf + ml*264 + (c-4)*32 + quad*8);   // X' ch 128..383
    #pragma unroll
    for (int ot = 0; ot < 16; ot++){
      bf16x8 afrag = *(const bf16x8*)(Ws + (ot*16 + col)*40 + quad*8);
      acc[ot] = __builtin_amdgcn_mfma_f32_16x16x32_bf16(afrag, bfrag, acc[ot], 0, 0, 0);
    }
  }
  // issue phase-2 prologue loads early: W2 chunk 0 + layer-2 params
  const int4* w2src = (const int4*)(W2g + (size_t)tid * HD);
  int4 v0r = w2src[0], v1r = w2src[1], v2r = w2src[2], v3r = w2src[3];
  float rb2 = b2[tid], rg2 = g2[tid], rbe2 = be2[tid];
  {
    float s1 = 0.f, s2 = 0.f;
    #pragma unroll
    for (int ot = 0; ot < 16; ot++)
      #pragma unroll
      for (int r = 0; r < 4; r++){
        int o = ot*16 + quad*4 + r;
        float v = acc[ot][r] + sB[o];
        acc[ot][r] = v;
        s1 += v; s2 += v*v;
      }
    s1 += __shfl_xor(s1, 16); s1 += __shfl_xor(s1, 32);
    s2 += __shfl_xor(s2, 16); s2 += __shfl_xor(s2, 32);
    float mu = s1 * (1.f/256.f);
    float rinv = rsqrtf(s2 * (1.f/256.f) - mu*mu + 1e-5f);
    bar_sync();        // ALL waves' X'/Xs reads drained before H overwrites Hbuf
    #pragma unroll
    for (int ot = 0; ot < 16; ot++){
      int ob = ot*16 + quad*4;
      ushort4 hv;
      hv.x = f2b(fmaxf((acc[ot][0] - mu) * rinv * sG[ob+0] + sBe[ob+0], 0.f));
      hv.y = f2b(fmaxf((acc[ot][1] - mu) * rinv * sG[ob+1] + sBe[ob+1], 0.f));
      hv.z = f2b(fmaxf((acc[ot][2] - mu) * rinv * sG[ob+2] + sBe[ob+2], 0.f));
      hv.w = f2b(fmaxf((acc[ot][3] - mu) * rinv * sG[ob+3] + sBe[ob+3], 0.f));
      *(ushort4*)(Hbuf + ml*264 + ot*16 + quad*4) = hv;
    }
  }
  bar_sync();          // H writes visible to all; layer-1 param reads drained
  sB[tid] = rb2; sG[tid] = rg2; sBe[tid] = rbe2;

  // ---------------- phase 2: out = relu(LN2(W2 @ H + b2)) ----------------
  #pragma unroll
  for (int i = 0; i < 16; i++) acc[i] = (f32x4)0.0f;
  for (int c = 0; c < 8; c++){
    bar_sync();        // previous chunk's Ws readers drained (iter 0: param writes too)
    {
      int4* d4 = (int4*)(Ws + tid * 40);
      d4[0] = v0r; d4[1] = v1r; d4[2] = v2r; d4[3] = v3r;
    }
    if (c + 1 < 8){
      v0r = w2src[(c+1)*4 + 0]; v1r = w2src[(c+1)*4 + 1];
      v2r = w2src[(c+1)*4 + 2]; v3r = w2src[(c+1)*4 + 3];
    }
    bar_sync();        // Ws writes visible
    bf16x8 bfrag = *(const bf16x8*)(Hbuf + ml*264 + c*32 + quad*8);
    #pragma unroll
    for (int ot = 0; ot < 16; ot++){
      bf16x8 afrag = *(const bf16x8*)(Ws + (ot*16 + col)*40 + quad*8);
      acc[ot] = __builtin_amdgcn_mfma_f32_16x16x32_bf16(afrag, bfrag, acc[ot], 0, 0, 0);
    }
  }
  float s1 = 0.f, s2 = 0.f;
  #pragma unroll
  for (int ot = 0; ot < 16; ot++)
    #pragma unroll
    for (int r = 0; r < 4; r++){
      int o = ot*16 + quad*4 + r;
      float v = acc[ot][r] + sB[o];
      acc[ot][r] = v;
      s1 += v; s2 += v*v;
    }
  s1 += __shfl_xor(s1, 16); s1 += __shfl_xor(s1, 32);
  s2 += __shfl_xor(s2, 16); s2 += __shfl_xor(s2, 32);
  float mu = s1 * (1.f/256.f);
  float rinv = rsqrtf(s2 * (1.f/256.f) - mu*mu + 1e-5f);
  size_t obase = (size_t)b * HD * NPT + n0 + w*16 + col;
  #pragma unroll
  for (int ot = 0; ot < 16; ot++)
    #pragma unroll
    for (int r = 0; r < 4; r++){
      int o = ot*16 + quad*4 + r;
      float v = (acc[ot][r] - mu) * rinv * sG[o] + sBe[o];
      outg[obase + (size_t)o * NPT] = fmaxf(v, 0.f);
    }
}

extern "C" void kernel_launch(void* const* d_in, const int* in_sizes, int n_in,
                              void* d_out, int out_size, void* d_ws, size_t ws_size,
                              hipStream_t stream){
  const float* coor1 = (const float*)d_in[0];
  const float* coor2 = (const float*)d_in[1];
  const float* fea1  = (const float*)d_in[2];
  const float* fea2  = (const float*)d_in[3];
  const unsigned char* pad = (const unsigned char*)d_in[4];
  const float* W1  = (const float*)d_in[5];
  const float* b1  = (const float*)d_in[6];
  const float* g1  = (const float*)d_in[7];
  const float* be1 = (const float*)d_in[8];
  const float* W2  = (const float*)d_in[9];
  const float* b2  = (const float*)d_in[10];
  const float* g2  = (const float*)d_in[11];
  const float* be2 = (const float*)d_in[12];
  float* out = (float*)d_out;

  // ws layout (~94.2 MB, proven footprint): | W1b | W2b | f2t | xpm | scratch
  // cv/cj/gs alias the old Hg region (knn-stage scratch only)
  char* ws = (char*)d_ws;
  unsigned short* W1b  = (unsigned short*)(ws + 1573120);
  unsigned short* W2b  = (unsigned short*)(ws + 1769728);
  unsigned short* f2t  = (unsigned short*)(ws + 1900800);
  unsigned short* xpm  = (unsigned short*)(ws + 10289408);
  float* cv            = (float*)(ws + 60621056);             // knn scratch
  int*   cj            = (int*)  (ws + 60621056 + 6291456);
  float4* gs           = (float4*)(ws + 60621056 + 16777216);

  gsrc_kernel<<<BB*SPT/256, 256, 0, stream>>>(coor2, pad, gs);
  main_kernel<<<NB_KNN + NB_CVT + NB_T2 + NB_T1, 256, 0, stream>>>(
      coor1, gs, cv, cj, W1, W2, W1b, fea2, f2t, fea1, xpm);
  mlp_fused_kernel<<<BB*NPT/64, 256, 0, stream>>>(
      cv, cj, f2t, xpm, W1b, W2b, b1, g1, be1, b2, g2, be2, out);
}